// Round 12
// baseline (1168.654 us; speedup 1.0000x reference)
//
#include <hip/hip_runtime.h>
#include <stdint.h>

typedef float f32x4 __attribute__((ext_vector_type(4)));
typedef int   i32x8 __attribute__((ext_vector_type(8)));

#define FP8_MAX_V 448.0f

// Pack 4 floats -> 4 OCP e4m3fn bytes, RNE, after reference-matching clip.
__device__ __forceinline__ uint32_t pack4_fp8(float a, float b, float c, float d) {
    a = fminf(fmaxf(a, -FP8_MAX_V), FP8_MAX_V);
    b = fminf(fmaxf(b, -FP8_MAX_V), FP8_MAX_V);
    c = fminf(fmaxf(c, -FP8_MAX_V), FP8_MAX_V);
    d = fminf(fmaxf(d, -FP8_MAX_V), FP8_MAX_V);
    int v = 0;
    v = __builtin_amdgcn_cvt_pk_fp8_f32(a, b, v, false);  // bytes 0,1
    v = __builtin_amdgcn_cvt_pk_fp8_f32(c, d, v, true);   // bytes 2,3
    return (uint32_t)v;
}

// Quantize fp32 -> fp8 e4m3fn AND write in MFMA-fragment-packed order.
// Packed layout: 2048-B block per (r16 = row>>4, kt = k>>7); within it,
// lane = ((k>>5)&3)*16 + (row&15) at byte lane*32 + (k&31). A wave's
// 16x16x128 fragment load is then base + lane*32 — fully coalesced.
__global__ void quant_pack_kernel(const float* __restrict__ in,
                                  uint8_t* __restrict__ out,
                                  const float* __restrict__ scale_ptr,
                                  uint32_t total4, int K4, int KT) {
    const float s = scale_ptr[0];
    uint32_t i = blockIdx.x * blockDim.x + threadIdx.x;
    const uint32_t stride = gridDim.x * blockDim.x;
    const float4* in4 = (const float4*)in;
    for (; i < total4; i += stride) {
        const int m  = i / K4;
        const int k0 = (i - (uint32_t)m * K4) << 2;
        float4 v = in4[i];
        const uint32_t q = pack4_fp8(v.x / s, v.y / s, v.z / s, v.w / s);
        const size_t addr = ((size_t)(m >> 4) * KT + (k0 >> 7)) * 2048
                          + (((k0 >> 5) & 3) << 9) + ((m & 15) << 5) + (k0 & 31);
        *(uint32_t*)(out + addr) = q;
    }
}

// Fragment-packed MX-fp8 GEMM: NO LDS, NO barriers — pure register-streaming.
// Round-10 kernel verified correct (bank-conflict 0, absmax 0.03125) but was
// occupancy-strangled: __launch_bounds__(256,2) pinned a 92-VGPR LDS-free
// kernel at 2 blocks/CU. A barrier-free kernel's ONLY latency hiding is TLP;
// this round raises the bound to (256,4) = 16 waves/CU = 4/SIMD.
// Block 128x128, 4 waves (2x2), wave tile 64x64, acc 4x4 16x16 frags.
// mfma_scale_f32_16x16x128_f8f6f4, E8M0 scale 127 (=1.0) == plain fp8.
__global__ __launch_bounds__(256, 4) void gemm_pk_kernel(
    const uint8_t* __restrict__ pA,   // packed [M/16][KT][2048]
    const uint8_t* __restrict__ pB,   // packed [N/16][KT][2048]
    const float* __restrict__ bias,   // [N]
    const float* __restrict__ s_in_p,
    const float* __restrict__ s_w_p,
    float* __restrict__ C,            // [M][N] fp32
    int M, int N, int K) {
    const int tid = threadIdx.x;
    const int w   = tid >> 6;   // wave 0..3
    const int l   = tid & 63;
    const int wr  = w >> 1;     // A rows [wr*64, +64)
    const int wc  = w & 1;      // B rows [wc*64, +64)
    const int lr  = l & 15;
    const int lg  = l >> 4;

    // XCD-bijective block swizzle: grid = 3584 = 8 * 448 = 32 * 112.
    const int cpx = (int)gridDim.x >> 3;
    const int swz = ((int)blockIdx.x & 7) * cpx + ((int)blockIdx.x >> 3);
    const int bm  = (swz & 31) << 7;   // M/128 = 32 tiles (pow2, fastest —
    const int bn  = (swz >> 5) << 7;   // 32 consecutive blocks share B panel)

    const float outscale = s_in_p[0] * s_w_p[0];
    const int KT = K >> 7;             // 32 K-tiles of 128 bytes (even)

    // Fragment base pointers: frag q (=mi/ni) of K-tile kt lives at
    // base + (q*KT + kt)*2048 + lane*32.
    const uint8_t* aBase = pA + ((size_t)((bm >> 4) + wr * 4) * KT) * 2048 + l * 32;
    const uint8_t* bBase = pB + ((size_t)((bn >> 4) + wc * 4) * KT) * 2048 + l * 32;

    f32x4 acc[4][4];
#pragma unroll
    for (int mi = 0; mi < 4; ++mi)
#pragma unroll
        for (int ni = 0; ni < 4; ++ni)
            acc[mi][ni] = (f32x4){0.f, 0.f, 0.f, 0.f};

    i32x8 aC[4], bC[4], aN[4], bN[4];

#define LOADT(AR, BR, KTI) do { \
    _Pragma("unroll") \
    for (int q = 0; q < 4; ++q) \
        AR[q] = *(const i32x8*)(aBase + ((size_t)q * KT + (KTI)) * 2048); \
    _Pragma("unroll") \
    for (int q = 0; q < 4; ++q) \
        BR[q] = *(const i32x8*)(bBase + ((size_t)q * KT + (KTI)) * 2048); \
} while (0)

#define MM(AR, BR) do { \
    _Pragma("unroll") \
    for (int mi = 0; mi < 4; ++mi) \
        _Pragma("unroll") \
        for (int ni = 0; ni < 4; ++ni) \
            acc[mi][ni] = __builtin_amdgcn_mfma_scale_f32_16x16x128_f8f6f4( \
                AR[mi], BR[ni], acc[mi][ni], 0, 0, 0, 127, 0, 127); \
} while (0)

    LOADT(aC, bC, 0);
    int kt = 0;
    for (; kt < KT - 2; kt += 2) {     // KT even; static dual buffers
        LOADT(aN, bN, kt + 1);
        MM(aC, bC);
        LOADT(aC, bC, kt + 2);
        MM(aN, bN);
    }
    LOADT(aN, bN, KT - 1);
    MM(aC, bC);
    MM(aN, bN);

    // Epilogue. 16x16 C/D layout: col = lane&15, row = (lane>>4)*4 + reg.
    const int crow0 = bm + wr * 64 + (lg << 2);
    const int ccol0 = bn + wc * 64 + lr;
#pragma unroll
    for (int ni = 0; ni < 4; ++ni) {
        const int col = ccol0 + ni * 16;
        const float bv = bias[col];
#pragma unroll
        for (int mi = 0; mi < 4; ++mi) {
            const int row = crow0 + mi * 16;
#pragma unroll
            for (int r = 0; r < 4; ++r)
                C[(size_t)(row + r) * N + col] = acc[mi][ni][r] * outscale + bv;
        }
    }
#undef LOADT
#undef MM
}

extern "C" void kernel_launch(void* const* d_in, const int* in_sizes, int n_in,
                              void* d_out, int out_size, void* d_ws, size_t ws_size,
                              hipStream_t stream) {
    const float* x    = (const float*)d_in[0];
    const float* wt   = (const float*)d_in[1];
    const float* bias = (const float*)d_in[2];
    const float* s_in = (const float*)d_in[3];
    const float* s_w  = (const float*)d_in[4];
    float* out = (float*)d_out;

    const long long xe = in_sizes[0];            // M*K
    const long long we = in_sizes[1];            // N*K
    const int N = in_sizes[2];
    const int K = (int)(we / N);
    const int M = (int)(xe / K);
    const int K4 = K >> 2;
    const int KT = K >> 7;

    uint8_t* qx = (uint8_t*)d_ws;                // packed M*K fp8
    uint8_t* qw = qx + xe;                       // packed N*K fp8

    quant_pack_kernel<<<2048, 256, 0, stream>>>(x,  qx, s_in,
                                                (uint32_t)(xe >> 2), K4, KT);
    quant_pack_kernel<<<2048, 256, 0, stream>>>(wt, qw, s_w,
                                                (uint32_t)(we >> 2), K4, KT);

    dim3 grid((M / 128) * (N / 128));            // 32*112 = 3584 (8 | 3584)
    gemm_pk_kernel<<<grid, 256, 0, stream>>>(qx, qw, bias, s_in, s_w, out,
                                             M, N, K);
}

// Round 13
// 462.957 us; speedup vs baseline: 2.5243x; 2.5243x over previous
//
#include <hip/hip_runtime.h>
#include <stdint.h>

typedef float f32x4 __attribute__((ext_vector_type(4)));
typedef int   i32x8 __attribute__((ext_vector_type(8)));
typedef long  i64x2 __attribute__((ext_vector_type(2)));

#define FP8_MAX_V 448.0f

// Pack 4 floats -> 4 OCP e4m3fn bytes, RNE, after reference-matching clip.
__device__ __forceinline__ uint32_t pack4_fp8(float a, float b, float c, float d) {
    a = fminf(fmaxf(a, -FP8_MAX_V), FP8_MAX_V);
    b = fminf(fmaxf(b, -FP8_MAX_V), FP8_MAX_V);
    c = fminf(fmaxf(c, -FP8_MAX_V), FP8_MAX_V);
    d = fminf(fmaxf(d, -FP8_MAX_V), FP8_MAX_V);
    int v = 0;
    v = __builtin_amdgcn_cvt_pk_fp8_f32(a, b, v, false);  // bytes 0,1
    v = __builtin_amdgcn_cvt_pk_fp8_f32(c, d, v, true);   // bytes 2,3
    return (uint32_t)v;
}

// Plain row-major fp8 quant (for A, staged via global_load_lds).
__global__ void quant_fp8_kernel(const float* __restrict__ in,
                                 uint32_t* __restrict__ out,
                                 const float* __restrict__ scale_ptr,
                                 long long n4) {
    const float s = scale_ptr[0];
    long long i = (long long)blockIdx.x * blockDim.x + threadIdx.x;
    const long long stride = (long long)gridDim.x * blockDim.x;
    const float4* in4 = (const float4*)in;
    for (; i < n4; i += stride) {
        float4 v = in4[i];
        out[i] = pack4_fp8(v.x / s, v.y / s, v.z / s, v.w / s);
    }
}

// Fragment-packed fp8 quant (for B, loaded direct-to-registers).
// 2048-B block per (r16 = row>>4, kt = k>>7); lane = ((k>>5)&3)*16 + (row&15)
// at byte lane*32 + (k&31). Wave frag load = base + lane*32, fully coalesced.
__global__ void quant_pack_kernel(const float* __restrict__ in,
                                  uint8_t* __restrict__ out,
                                  const float* __restrict__ scale_ptr,
                                  uint32_t total4, int K4, int KT) {
    const float s = scale_ptr[0];
    uint32_t i = blockIdx.x * blockDim.x + threadIdx.x;
    const uint32_t stride = gridDim.x * blockDim.x;
    const float4* in4 = (const float4*)in;
    for (; i < total4; i += stride) {
        const int m  = i / K4;
        const int k0 = (i - (uint32_t)m * K4) << 2;
        float4 v = in4[i];
        const uint32_t q = pack4_fp8(v.x / s, v.y / s, v.z / s, v.w / s);
        const size_t addr = ((size_t)(m >> 4) * KT + (k0 >> 7)) * 2048
                          + (((k0 >> 5) & 3) << 9) + ((m & 15) << 5) + (k0 & 31);
        *(uint32_t*)(out + addr) = q;
    }
}

// HYBRID MX-fp8 GEMM: A via LDS (ring-2, counted vmcnt), B fragment-packed
// DIRECT from global to registers (r10-verified layout, coalesced, no LDS).
// LDS pipe per block-K-tile drops 96+48 KiB (r6, ~287us floor = its wall)
// -> 32+32 KiB (~59us floor), under the 103us MX MFMA floor.
// BM=256, BN=128, BK=128 B. 512 thr / 8 waves (4M x 2N), wave 64x64,
// acc 4x4 16x16 frags (64 AGPR). mfma_scale_f32_16x16x128_f8f6f4, E8M0
// scale 127 (=1.0) == plain fp8 numerics.
// A swizzle: 16B slot = chunk ^ (row&7) on global SOURCE + ds_read (rule #21).
// Per K-tile: {STAGE_A(T+1) 4 issues; LOAD_B(T+1) 4 issues; 8 ds_read;
// lgkmcnt(0); 16 MFMA; vmcnt(4) [A landed, B in flight]; s_barrier}.
__global__ __launch_bounds__(512, 2) void gemm_hy_kernel(
    const uint8_t* __restrict__ qA,   // row-major [M][K] fp8
    const uint8_t* __restrict__ pB,   // packed [N/16][KT][2048] fp8
    const float* __restrict__ bias,   // [N]
    const float* __restrict__ s_in_p,
    const float* __restrict__ s_w_p,
    float* __restrict__ C,            // [M][N] fp32
    int M, int N, int K) {
    __shared__ uint8_t lds[2][32768]; // A ring-2: [256 rows][128 B]

    const int tid = threadIdx.x;
    const int w   = tid >> 6;   // wave 0..7
    const int l   = tid & 63;
    const int wr  = w >> 1;     // A rows [wr*64, +64)
    const int wc  = w & 1;      // B rows [wc*64, +64)
    const int lr  = l & 15;
    const int lg  = l >> 4;
    const int lsw = lr & 7;

    // XCD-bijective block swizzle: grid = 1792 = 8 * 224.
    const int cpx = (int)gridDim.x >> 3;
    const int swz = ((int)blockIdx.x & 7) * cpx + ((int)blockIdx.x >> 3);
    const int bm  = (swz & 15) << 8;   // M/256 = 16 tiles
    const int bn  = (swz >> 4) << 7;   // N/128 = 112 tiles

    const float outscale = s_in_p[0] * s_w_p[0];
    const int NT = K >> 7;             // 32 K-tiles (even)
    const int KT = NT;

    // A ds_read: two b128 at swizzled slots of the fragment row.
    const int off0 = (((lg << 1) ^ lsw) << 4);
    const int off1 = off0 ^ 16;

    f32x4 acc[4][4];
#pragma unroll
    for (int mi = 0; mi < 4; ++mi)
#pragma unroll
        for (int ni = 0; ni < 4; ++ni)
            acc[mi][ni] = (f32x4){0.f, 0.f, 0.f, 0.f};

    // A staging: 512 thr x 16 B = 8 KiB = 64 rows/issue; 4 issues/tile.
    const int srow = tid >> 3;                        // 0..63
    const int sc   = (((tid & 7) ^ (srow & 7)) << 4);
    const uint8_t* sA = qA + (size_t)(bm + srow) * K + sc;
    const int dstw = w << 10;   // wave base; HW adds lane*16

    // B packed fragment base: frag ni of tile kt at
    // pB + (((bn>>4) + wc*4 + ni)*KT + kt)*2048 + lane*32.
    const uint8_t* bBase = pB + ((size_t)((bn >> 4) + wc * 4) * KT) * 2048 + l * 32;

    union frag { i32x8 v; i64x2 h[2]; };
    frag b0[4], b1[4];

#define STAGE_A(SL, KB) do { \
    _Pragma("unroll") \
    for (int i = 0; i < 4; ++i) { \
        __builtin_amdgcn_global_load_lds( \
            (const __attribute__((address_space(1))) void*)(sA + (size_t)(i * 64) * K + (KB)), \
            (__attribute__((address_space(3))) void*)(&lds[SL][0] + i * 8192 + dstw), 16, 0, 0); \
    } } while (0)

#define LOAD_B(BUF, KTI) do { \
    _Pragma("unroll") \
    for (int q = 0; q < 4; ++q) \
        BUF[q].v = *(const i32x8*)(bBase + ((size_t)q * KT + (KTI)) * 2048); \
} while (0)

#define TILE_BODY(TT, SLOT, BCUR, BNXT) do { \
    const int tn = ((TT) + 1 < NT) ? (TT) + 1 : 0; \
    STAGE_A((SLOT) ^ 1, (size_t)tn << 7); \
    LOAD_B(BNXT, tn); \
    __builtin_amdgcn_sched_barrier(0); \
    const uint8_t* sbase = &lds[SLOT][0]; \
    frag ua[4]; \
    _Pragma("unroll") \
    for (int mi = 0; mi < 4; ++mi) { \
        const uint8_t* p = sbase + ((wr * 64 + mi * 16 + lr) << 7); \
        ua[mi].h[0] = *(const i64x2*)(p + off0); \
        ua[mi].h[1] = *(const i64x2*)(p + off1); \
    } \
    asm volatile("s_waitcnt lgkmcnt(0)" ::: "memory"); \
    __builtin_amdgcn_sched_barrier(0); \
    __builtin_amdgcn_s_setprio(1); \
    _Pragma("unroll") \
    for (int mi = 0; mi < 4; ++mi) \
        _Pragma("unroll") \
        for (int ni = 0; ni < 4; ++ni) \
            acc[mi][ni] = __builtin_amdgcn_mfma_scale_f32_16x16x128_f8f6f4( \
                ua[mi].v, BCUR[ni].v, acc[mi][ni], 0, 0, 0, 127, 0, 127); \
    __builtin_amdgcn_s_setprio(0); \
    asm volatile("s_waitcnt vmcnt(4)" ::: "memory"); \
    __builtin_amdgcn_s_barrier(); \
} while (0)

    // Prologue: A(0)->slot0 (4 issues), B(0)->b0 (4 issues); vmcnt(4)
    // drains the A stages (B's first use gets a compiler-counted wait).
    STAGE_A(0, 0);
    LOAD_B(b0, 0);
    asm volatile("s_waitcnt vmcnt(4)" ::: "memory");
    __builtin_amdgcn_s_barrier();

    for (int T = 0; T < NT; T += 2) {  // NT even; static buffer naming
        TILE_BODY(T,     0, b0, b1);
        TILE_BODY(T + 1, 1, b1, b0);
    }

    // Epilogue. 16x16 C/D layout: col = lane&15, row = (lane>>4)*4 + reg.
    const int crow0 = bm + wr * 64 + (lg << 2);
    const int ccol0 = bn + wc * 64 + lr;
#pragma unroll
    for (int ni = 0; ni < 4; ++ni) {
        const int col = ccol0 + ni * 16;
        const float bv = bias[col];
#pragma unroll
        for (int mi = 0; mi < 4; ++mi) {
            const int row = crow0 + mi * 16;
#pragma unroll
            for (int r = 0; r < 4; ++r)
                C[(size_t)(row + r) * N + col] = acc[mi][ni][r] * outscale + bv;
        }
    }
#undef STAGE_A
#undef LOAD_B
#undef TILE_BODY
}

extern "C" void kernel_launch(void* const* d_in, const int* in_sizes, int n_in,
                              void* d_out, int out_size, void* d_ws, size_t ws_size,
                              hipStream_t stream) {
    const float* x    = (const float*)d_in[0];
    const float* wt   = (const float*)d_in[1];
    const float* bias = (const float*)d_in[2];
    const float* s_in = (const float*)d_in[3];
    const float* s_w  = (const float*)d_in[4];
    float* out = (float*)d_out;

    const long long xe = in_sizes[0];            // M*K
    const long long we = in_sizes[1];            // N*K
    const int N = in_sizes[2];
    const int K = (int)(we / N);
    const int M = (int)(xe / K);
    const int K4 = K >> 2;
    const int KT = K >> 7;

    uint8_t* qx = (uint8_t*)d_ws;                // row-major M*K fp8 (A)
    uint8_t* qw = qx + xe;                       // packed N*K fp8 (B)

    quant_fp8_kernel<<<2048, 256, 0, stream>>>(x, (uint32_t*)qx, s_in, xe >> 2);
    quant_pack_kernel<<<2048, 256, 0, stream>>>(wt, qw, s_w,
                                                (uint32_t)(we >> 2), K4, KT);

    dim3 grid((M / 256) * (N / 128));            // 16*112 = 1792 (8 | 1792)
    gemm_hy_kernel<<<grid, 512, 0, stream>>>(qx, qw, bias, s_in, s_w, out,
                                             M, N, K);
}